// Round 7
// baseline (1067.208 us; speedup 1.0000x reference)
//
#include <hip/hip_runtime.h>

typedef unsigned short ushort_t;
typedef __attribute__((ext_vector_type(8))) short bf16x8;   // 8 bf16 = 4 VGPRs
typedef __attribute__((ext_vector_type(4))) float f32x4;

#define T_SEQ 2048

__device__ __forceinline__ ushort_t f2bf(float f) {
    unsigned u = __float_as_uint(f);
    unsigned r = u + 0x7FFFu + ((u >> 16) & 1u);
    return (ushort_t)(r >> 16);
}
__device__ __forceinline__ unsigned pack2(float a, float b) {
    return (unsigned)f2bf(a) | ((unsigned)f2bf(b) << 16);
}

// ---- fp32 -> bf16 for both activation tensors (blockIdx.y selects) ----
__global__ __launch_bounds__(256) void cvt_bf16_2(const float* __restrict__ a,
                                                  const float* __restrict__ b,
                                                  ushort_t* __restrict__ oa,
                                                  ushort_t* __restrict__ ob) {
    const float* in = blockIdx.y ? b : a;
    ushort_t* out = blockIdx.y ? ob : oa;
    size_t i = ((size_t)blockIdx.x * 256 + threadIdx.x) * 8;
    float4 f0 = *(const float4*)(in + i);
    float4 f1 = *(const float4*)(in + i + 4);
    uint4 w;
    w.x = pack2(f0.x, f0.y); w.y = pack2(f0.z, f0.w);
    w.z = pack2(f1.x, f1.y); w.w = pack2(f1.z, f1.w);
    *(uint4*)(out + i) = w;
}

// ---- all 4 weights: fp32 [k][n] -> bf16 transposed out[n][k] (blockIdx.z selects) ----
__global__ __launch_bounds__(256) void cvt_w4(
    const float* __restrict__ W0, const float* __restrict__ W1,
    const float* __restrict__ W2, const float* __restrict__ W3,
    ushort_t* __restrict__ O0, ushort_t* __restrict__ O1,
    ushort_t* __restrict__ O2, ushort_t* __restrict__ O3) {
    __shared__ ushort_t Ls[64][72];
    const int z = blockIdx.z;
    const float* W = (z == 0) ? W0 : (z == 1) ? W1 : (z == 2) ? W2 : W3;
    ushort_t* out  = (z == 0) ? O0 : (z == 1) ? O1 : (z == 2) ? O2 : O3;
    const int t = threadIdx.x;
    const int k0 = blockIdx.y * 64, n0 = blockIdx.x * 64;
    {
        const int r = t >> 2, c = (t & 3) * 16;
        const float* p = W + (size_t)(k0 + r) * 1024 + n0 + c;
        float4 a = *(const float4*)p, b = *(const float4*)(p + 4);
        float4 c2 = *(const float4*)(p + 8), d = *(const float4*)(p + 12);
        uint4 w0, w1;
        w0.x = pack2(a.x, a.y); w0.y = pack2(a.z, a.w);
        w0.z = pack2(b.x, b.y); w0.w = pack2(b.z, b.w);
        w1.x = pack2(c2.x, c2.y); w1.y = pack2(c2.z, c2.w);
        w1.z = pack2(d.x, d.y); w1.w = pack2(d.z, d.w);
        *(uint4*)&Ls[r][c] = w0;
        *(uint4*)&Ls[r][c + 8] = w1;
    }
    __syncthreads();
    {
        const int nn = t >> 2, kc = (t & 3) * 16;
        unsigned u[8];
#pragma unroll
        for (int a2 = 0; a2 < 8; ++a2)
            u[a2] = (unsigned)Ls[kc + 2 * a2][nn] | ((unsigned)Ls[kc + 2 * a2 + 1][nn] << 16);
        uint4 w0 = {u[0], u[1], u[2], u[3]}, w1 = {u[4], u[5], u[6], u[7]};
        ushort_t* op = out + (size_t)(n0 + nn) * 1024 + k0 + kc;
        *(uint4*)op = w0;
        *(uint4*)(op + 8) = w1;
    }
}

// ---- V bf16 [b*2048+t][ldin] -> VT [((b*16+h)*64+s)][2048] ----
__global__ __launch_bounds__(256) void transpose_v(const ushort_t* __restrict__ Vin, int ldin,
                                                   ushort_t* __restrict__ VT) {
    __shared__ ushort_t Ls[64][72];
    const int t = threadIdx.x;
    const int t0 = blockIdx.x * 64;
    const int h = blockIdx.y, b = blockIdx.z;
    {
        const int r = t >> 2, c = (t & 3) * 16;
        const ushort_t* p = Vin + (size_t)(b * T_SEQ + t0 + r) * ldin + h * 64 + c;
        *(uint4*)&Ls[r][c] = *(const uint4*)p;
        *(uint4*)&Ls[r][c + 8] = *(const uint4*)(p + 8);
    }
    __syncthreads();
    {
        const int s = t >> 2, tc = (t & 3) * 16;
        unsigned u[8];
#pragma unroll
        for (int a2 = 0; a2 < 8; ++a2)
            u[a2] = (unsigned)Ls[tc + 2 * a2][s] | ((unsigned)Ls[tc + 2 * a2 + 1][s] << 16);
        uint4 w0 = {u[0], u[1], u[2], u[3]}, w1 = {u[4], u[5], u[6], u[7]};
        ushort_t* op = VT + ((size_t)(b * 16 + h) * 64 + s) * T_SEQ + t0 + tc;
        *(uint4*)op = w0;
        *(uint4*)(op + 8) = w1;
    }
}

// ---- GEMM: C = scale * A[M,K] * Bt[N,K]^T; 128x128 tile, BK=64,
// register-prefetch double-buffer so HBM latency hides under MFMA. ----
__global__ __launch_bounds__(256) void gemm128(
    const ushort_t* __restrict__ A, const ushort_t* __restrict__ Bt,
    void* __restrict__ Cv, int M, int N, int K, float scale, int cF32)
{
    __shared__ ushort_t As[128][64];
    __shared__ ushort_t Bs[128][64];
    const int t = threadIdx.x;
    const int lane = t & 63, wave = t >> 6;
    const int col = lane & 15, quad = lane >> 4;
    const int wm = wave & 1, wn = wave >> 1;
    const int m0 = blockIdx.y * 128, n0 = blockIdx.x * 128;

    f32x4 acc[4][4];
#pragma unroll
    for (int i = 0; i < 4; ++i)
#pragma unroll
        for (int j = 0; j < 4; ++j) acc[i][j] = (f32x4){0.f, 0.f, 0.f, 0.f};

    uint4 pa[4], pb[4];
#pragma unroll
    for (int j = 0; j < 4; ++j) {
        const int c = j * 256 + t, row = c >> 3, cc = (c & 7) * 8;
        pa[j] = *(const uint4*)(A + (size_t)(m0 + row) * K + cc);
        pb[j] = *(const uint4*)(Bt + (size_t)(n0 + row) * K + cc);
    }

    for (int k0 = 0; k0 < K; k0 += 64) {
#pragma unroll
        for (int j = 0; j < 4; ++j) {
            const int c = j * 256 + t, row = c >> 3, cc = (c & 7) * 8;
            *(uint4*)&As[row][cc] = pa[j];
            *(uint4*)&Bs[row][cc] = pb[j];
        }
        __syncthreads();
        if (k0 + 64 < K) {
#pragma unroll
            for (int j = 0; j < 4; ++j) {
                const int c = j * 256 + t, row = c >> 3, cc = (c & 7) * 8;
                pa[j] = *(const uint4*)(A + (size_t)(m0 + row) * K + k0 + 64 + cc);
                pb[j] = *(const uint4*)(Bt + (size_t)(n0 + row) * K + k0 + 64 + cc);
            }
        }
#pragma unroll
        for (int kk = 0; kk < 2; ++kk) {
            bf16x8 a[4], b[4];
#pragma unroll
            for (int i = 0; i < 4; ++i)
                a[i] = *(const bf16x8*)&As[wm * 64 + i * 16 + col][kk * 32 + quad * 8];
#pragma unroll
            for (int j = 0; j < 4; ++j)
                b[j] = *(const bf16x8*)&Bs[wn * 64 + j * 16 + col][kk * 32 + quad * 8];
#pragma unroll
            for (int i = 0; i < 4; ++i)
#pragma unroll
                for (int j = 0; j < 4; ++j)
                    acc[i][j] = __builtin_amdgcn_mfma_f32_16x16x32_bf16(a[i], b[j], acc[i][j], 0, 0, 0);
        }
        __syncthreads();
    }
#pragma unroll
    for (int i = 0; i < 4; ++i) {
        const int row = m0 + wm * 64 + i * 16 + quad * 4;
#pragma unroll
        for (int j = 0; j < 4; ++j) {
            const int cc = n0 + wn * 64 + j * 16 + col;
#pragma unroll
            for (int r = 0; r < 4; ++r) {
                float v = acc[i][j][r] * scale;
                if (cF32) ((float*)Cv)[(size_t)(row + r) * N + cc] = v;
                else      ((ushort_t*)Cv)[(size_t)(row + r) * N + cc] = f2bf(v);
            }
        }
    }
}

// ---- flash attention, no-max softmax (clamped), no in-loop barriers/shuffles.
// K, V^T fragments read directly from global (L2-resident). KV-tile 128. ----
__global__ __launch_bounds__(256) void attn_nomax(
    const ushort_t* __restrict__ Q, int ldq,
    const ushort_t* __restrict__ K, int ldk,
    const ushort_t* __restrict__ VT,
    const float* __restrict__ Mask,
    ushort_t* __restrict__ O, int ldo)
{
    __shared__ ushort_t Qs[64][72];
    __shared__ ushort_t Ps[64][72];

    const int t = threadIdx.x;
    const int lane = t & 63, wave = t >> 6;
    const int col = lane & 15, quad = lane >> 4;
    const int q0 = blockIdx.x * 64;
    const int h = blockIdx.y, n = blockIdx.z;

    {   // stage Q once
        const int r = t >> 2, c = (t & 3) * 16;
        const ushort_t* p = Q + (size_t)(n * T_SEQ + q0 + r) * ldq + h * 64 + c;
        *(uint4*)&Qs[r][c]     = *(const uint4*)p;
        *(uint4*)&Qs[r][c + 8] = *(const uint4*)(p + 8);
    }
    __syncthreads();
    const bf16x8 qa0 = *(const bf16x8*)&Qs[wave * 16 + col][quad * 8];
    const bf16x8 qa1 = *(const bf16x8*)&Qs[wave * 16 + col][32 + quad * 8];

    f32x4 o_acc[4];
#pragma unroll
    for (int i = 0; i < 4; ++i) o_acc[i] = (f32x4){0.f, 0.f, 0.f, 0.f};
    float l_run[4] = {0.f, 0.f, 0.f, 0.f};

    const float* Mrow = Mask + ((size_t)((n * 16 + h) * T_SEQ) + q0 + wave * 16 + quad * 4) * T_SEQ;
    const ushort_t* Kb  = K + (size_t)(n * T_SEQ) * ldk + h * 64;            // + kv*ldk
    const ushort_t* VTb = VT + ((size_t)(n * 16 + h) * 64) * T_SEQ;         // + s*T_SEQ + kv

    for (int kt = 0; kt < T_SEQ / 128; ++kt) {
        const int kv0 = kt * 128;

        // mask prefetch (independent; overlaps K-fragment latency)
        float mk[8][4];
#pragma unroll
        for (int nt = 0; nt < 8; ++nt)
#pragma unroll
            for (int r = 0; r < 4; ++r)
                mk[nt][r] = Mrow[(size_t)r * T_SEQ + kv0 + nt * 16 + col];

        // S = Q.K^T, fragments straight from global
        f32x4 s_acc[8];
#pragma unroll
        for (int nt = 0; nt < 8; ++nt) {
            const ushort_t* kp = Kb + (size_t)(kv0 + nt * 16 + col) * ldk;
            bf16x8 kb0 = *(const bf16x8*)(kp + quad * 8);
            bf16x8 kb1 = *(const bf16x8*)(kp + 32 + quad * 8);
            f32x4 z = (f32x4){0.f, 0.f, 0.f, 0.f};
            z = __builtin_amdgcn_mfma_f32_16x16x32_bf16(qa0, kb0, z, 0, 0, 0);
            z = __builtin_amdgcn_mfma_f32_16x16x32_bf16(qa1, kb1, z, 0, 0, 0);
#pragma unroll
            for (int r = 0; r < 4; ++r)
                z[r] = fminf(z[r] - 1e9f * mk[nt][r], 60.f);   // clamp guards exp overflow
            s_acc[nt] = z;
        }
        // exp (no max subtraction) + per-lane partial row-sums
#pragma unroll
        for (int nt = 0; nt < 8; ++nt)
#pragma unroll
            for (int r = 0; r < 4; ++r) {
                float p = __expf(s_acc[nt][r]);
                s_acc[nt][r] = p;
                l_run[r] += p;
            }

        // PV in two 64-col chunks; Ps rows are wave-private -> no barrier
#pragma unroll
        for (int ch = 0; ch < 2; ++ch) {
#pragma unroll
            for (int nt = 0; nt < 4; ++nt)
#pragma unroll
                for (int r = 0; r < 4; ++r)
                    Ps[wave * 16 + quad * 4 + r][nt * 16 + col] = f2bf(s_acc[ch * 4 + nt][r]);
            bf16x8 pa0 = *(const bf16x8*)&Ps[wave * 16 + col][quad * 8];
            bf16x8 pa1 = *(const bf16x8*)&Ps[wave * 16 + col][32 + quad * 8];
#pragma unroll
            for (int st = 0; st < 4; ++st) {
                const ushort_t* vp = VTb + (size_t)(st * 16 + col) * T_SEQ + kv0 + ch * 64;
                bf16x8 vb0 = *(const bf16x8*)(vp + quad * 8);
                bf16x8 vb1 = *(const bf16x8*)(vp + 32 + quad * 8);
                o_acc[st] = __builtin_amdgcn_mfma_f32_16x16x32_bf16(pa0, vb0, o_acc[st], 0, 0, 0);
                o_acc[st] = __builtin_amdgcn_mfma_f32_16x16x32_bf16(pa1, vb1, o_acc[st], 0, 0, 0);
            }
        }
    }

    // epilogue: 16-lane row-sum reduction, normalize, store
#pragma unroll
    for (int r = 0; r < 4; ++r) {
        float l = l_run[r];
#pragma unroll
        for (int off = 1; off < 16; off <<= 1) l += __shfl_xor(l, off);
        float inv = 1.0f / (l + 1e-30f);
        int qrow = q0 + wave * 16 + quad * 4 + r;
        size_t base = (size_t)(n * T_SEQ + qrow) * ldo + h * 64;
#pragma unroll
        for (int st = 0; st < 4; ++st)
            O[base + st * 16 + col] = f2bf(o_acc[st][r] * inv);
    }
}

extern "C" void kernel_launch(void* const* d_in, const int* in_sizes, int n_in,
                              void* d_out, int out_size, void* d_ws, size_t ws_size,
                              hipStream_t stream) {
    const float* q_seqs = (const float*)d_in[0];
    const float* r_seqs = (const float*)d_in[1];
    const float* mask   = (const float*)d_in[2];
    const float* Wq     = (const float*)d_in[3];
    const float* Wk     = (const float*)d_in[4];
    const float* Wv     = (const float*)d_in[5];
    const float* Wo     = (const float*)d_in[6];

    const size_t R = 4194304;  // region stride in ushorts (8 MiB)
    ushort_t* ws = (ushort_t*)d_ws;
    ushort_t* bfQ  = ws;            // R0: q_seqs bf16; later reused as wsO
    ushort_t* bfR  = ws + R;        // R1: r_seqs bf16; later reused as wsVT
    ushort_t* WqT  = ws + 2 * R;    // R2: WqT | WkvT(2048 rows) | WoT
    ushort_t* WkvT = WqT + 1048576;
    ushort_t* WoT  = WqT + 3145728;
    ushort_t* wsQ  = ws + 3 * R;    // R3
    ushort_t* wsKV = ws + 4 * R;    // R4+R5: [4096][2048]
    ushort_t* wsVT = bfR;
    ushort_t* wsO  = bfQ;

    dim3 blk(256);

    hipLaunchKernelGGL(cvt_bf16_2, dim3(2048, 2), blk, 0, stream, q_seqs, r_seqs, bfQ, bfR);
    hipLaunchKernelGGL(cvt_w4, dim3(16, 16, 4), blk, 0, stream,
                       Wq, Wk, Wv, Wo, WqT, WkvT, WkvT + 1048576, WoT);

    hipLaunchKernelGGL(gemm128, dim3(8, 32), blk, 0, stream,
                       bfQ, WqT, (void*)wsQ, 4096, 1024, 1024, 0.125f, 0);
    hipLaunchKernelGGL(gemm128, dim3(16, 32), blk, 0, stream,
                       bfR, WkvT, (void*)wsKV, 4096, 2048, 1024, 1.0f, 0);

    hipLaunchKernelGGL(transpose_v, dim3(32, 16, 2), blk, 0, stream,
                       wsKV + 1024, 2048, wsVT);

    hipLaunchKernelGGL(attn_nomax, dim3(32, 16, 2), blk, 0, stream,
                       wsQ, 1024, wsKV, 2048, wsVT, mask, wsO, 1024);

    hipLaunchKernelGGL(gemm128, dim3(8, 32), blk, 0, stream,
                       wsO, WoT, d_out, 4096, 1024, 1024, 1.0f, 1);
}

// Round 8
// 1007.372 us; speedup vs baseline: 1.0594x; 1.0594x over previous
//
#include <hip/hip_runtime.h>

typedef unsigned short ushort_t;
typedef __attribute__((ext_vector_type(8))) short bf16x8;   // 8 bf16 = 4 VGPRs
typedef __attribute__((ext_vector_type(4))) float f32x4;

#define T_SEQ 2048

__device__ __forceinline__ ushort_t f2bf(float f) {
    unsigned u = __float_as_uint(f);
    unsigned r = u + 0x7FFFu + ((u >> 16) & 1u);
    return (ushort_t)(r >> 16);
}
__device__ __forceinline__ unsigned pack2(float a, float b) {
    return (unsigned)f2bf(a) | ((unsigned)f2bf(b) << 16);
}

// ---- fp32 -> bf16 for both activation tensors (blockIdx.y selects) ----
__global__ __launch_bounds__(256) void cvt_bf16_2(const float* __restrict__ a,
                                                  const float* __restrict__ b,
                                                  ushort_t* __restrict__ oa,
                                                  ushort_t* __restrict__ ob) {
    const float* in = blockIdx.y ? b : a;
    ushort_t* out = blockIdx.y ? ob : oa;
    size_t i = ((size_t)blockIdx.x * 256 + threadIdx.x) * 8;
    float4 f0 = *(const float4*)(in + i);
    float4 f1 = *(const float4*)(in + i + 4);
    uint4 w;
    w.x = pack2(f0.x, f0.y); w.y = pack2(f0.z, f0.w);
    w.z = pack2(f1.x, f1.y); w.w = pack2(f1.z, f1.w);
    *(uint4*)(out + i) = w;
}

// ---- all 4 weights: fp32 [k][n] -> bf16 transposed out[n][k] (blockIdx.z selects) ----
__global__ __launch_bounds__(256) void cvt_w4(
    const float* __restrict__ W0, const float* __restrict__ W1,
    const float* __restrict__ W2, const float* __restrict__ W3,
    ushort_t* __restrict__ O0, ushort_t* __restrict__ O1,
    ushort_t* __restrict__ O2, ushort_t* __restrict__ O3) {
    __shared__ ushort_t Ls[64][72];
    const int z = blockIdx.z;
    const float* W = (z == 0) ? W0 : (z == 1) ? W1 : (z == 2) ? W2 : W3;
    ushort_t* out  = (z == 0) ? O0 : (z == 1) ? O1 : (z == 2) ? O2 : O3;
    const int t = threadIdx.x;
    const int k0 = blockIdx.y * 64, n0 = blockIdx.x * 64;
    {
        const int r = t >> 2, c = (t & 3) * 16;
        const float* p = W + (size_t)(k0 + r) * 1024 + n0 + c;
        float4 a = *(const float4*)p, b = *(const float4*)(p + 4);
        float4 c2 = *(const float4*)(p + 8), d = *(const float4*)(p + 12);
        uint4 w0, w1;
        w0.x = pack2(a.x, a.y); w0.y = pack2(a.z, a.w);
        w0.z = pack2(b.x, b.y); w0.w = pack2(b.z, b.w);
        w1.x = pack2(c2.x, c2.y); w1.y = pack2(c2.z, c2.w);
        w1.z = pack2(d.x, d.y); w1.w = pack2(d.z, d.w);
        *(uint4*)&Ls[r][c] = w0;
        *(uint4*)&Ls[r][c + 8] = w1;
    }
    __syncthreads();
    {
        const int nn = t >> 2, kc = (t & 3) * 16;
        unsigned u[8];
#pragma unroll
        for (int a2 = 0; a2 < 8; ++a2)
            u[a2] = (unsigned)Ls[kc + 2 * a2][nn] | ((unsigned)Ls[kc + 2 * a2 + 1][nn] << 16);
        uint4 w0 = {u[0], u[1], u[2], u[3]}, w1 = {u[4], u[5], u[6], u[7]};
        ushort_t* op = out + (size_t)(n0 + nn) * 1024 + k0 + kc;
        *(uint4*)op = w0;
        *(uint4*)(op + 8) = w1;
    }
}

// ---- V bf16 [b*2048+t][ldin] -> VT [((b*16+h)*64+s)][2048] ----
__global__ __launch_bounds__(256) void transpose_v(const ushort_t* __restrict__ Vin, int ldin,
                                                   ushort_t* __restrict__ VT) {
    __shared__ ushort_t Ls[64][72];
    const int t = threadIdx.x;
    const int t0 = blockIdx.x * 64;
    const int h = blockIdx.y, b = blockIdx.z;
    {
        const int r = t >> 2, c = (t & 3) * 16;
        const ushort_t* p = Vin + (size_t)(b * T_SEQ + t0 + r) * ldin + h * 64 + c;
        *(uint4*)&Ls[r][c] = *(const uint4*)p;
        *(uint4*)&Ls[r][c + 8] = *(const uint4*)(p + 8);
    }
    __syncthreads();
    {
        const int s = t >> 2, tc = (t & 3) * 16;
        unsigned u[8];
#pragma unroll
        for (int a2 = 0; a2 < 8; ++a2)
            u[a2] = (unsigned)Ls[tc + 2 * a2][s] | ((unsigned)Ls[tc + 2 * a2 + 1][s] << 16);
        uint4 w0 = {u[0], u[1], u[2], u[3]}, w1 = {u[4], u[5], u[6], u[7]};
        ushort_t* op = VT + ((size_t)(b * 16 + h) * 64 + s) * T_SEQ + t0 + tc;
        *(uint4*)op = w0;
        *(uint4*)(op + 8) = w1;
    }
}

// ---- GEMM: C = scale * A[M,K] * Bt[N,K]^T; 128x128 tile, BK=64,
// register-prefetch double-buffer (load k+1 while MFMAs consume tile k). ----
__global__ __launch_bounds__(256) void gemm128(
    const ushort_t* __restrict__ A, const ushort_t* __restrict__ Bt,
    void* __restrict__ Cv, int M, int N, int K, float scale, int cF32)
{
    __shared__ ushort_t As[128][64];
    __shared__ ushort_t Bs[128][64];
    const int t = threadIdx.x;
    const int lane = t & 63, wave = t >> 6;
    const int col = lane & 15, quad = lane >> 4;
    const int wm = wave & 1, wn = wave >> 1;
    const int m0 = blockIdx.y * 128, n0 = blockIdx.x * 128;

    f32x4 acc[4][4];
#pragma unroll
    for (int i = 0; i < 4; ++i)
#pragma unroll
        for (int j = 0; j < 4; ++j) acc[i][j] = (f32x4){0.f, 0.f, 0.f, 0.f};

    uint4 pa[4], pb[4];
#pragma unroll
    for (int j = 0; j < 4; ++j) {
        const int c = j * 256 + t, row = c >> 3, cc = (c & 7) * 8;
        pa[j] = *(const uint4*)(A + (size_t)(m0 + row) * K + cc);
        pb[j] = *(const uint4*)(Bt + (size_t)(n0 + row) * K + cc);
    }

    for (int k0 = 0; k0 < K; k0 += 64) {
#pragma unroll
        for (int j = 0; j < 4; ++j) {
            const int c = j * 256 + t, row = c >> 3, cc = (c & 7) * 8;
            *(uint4*)&As[row][cc] = pa[j];
            *(uint4*)&Bs[row][cc] = pb[j];
        }
        __syncthreads();
        if (k0 + 64 < K) {
#pragma unroll
            for (int j = 0; j < 4; ++j) {
                const int c = j * 256 + t, row = c >> 3, cc = (c & 7) * 8;
                pa[j] = *(const uint4*)(A + (size_t)(m0 + row) * K + k0 + 64 + cc);
                pb[j] = *(const uint4*)(Bt + (size_t)(n0 + row) * K + k0 + 64 + cc);
            }
        }
#pragma unroll
        for (int kk = 0; kk < 2; ++kk) {
            bf16x8 a[4], b[4];
#pragma unroll
            for (int i = 0; i < 4; ++i)
                a[i] = *(const bf16x8*)&As[wm * 64 + i * 16 + col][kk * 32 + quad * 8];
#pragma unroll
            for (int j = 0; j < 4; ++j)
                b[j] = *(const bf16x8*)&Bs[wn * 64 + j * 16 + col][kk * 32 + quad * 8];
#pragma unroll
            for (int i = 0; i < 4; ++i)
#pragma unroll
                for (int j = 0; j < 4; ++j)
                    acc[i][j] = __builtin_amdgcn_mfma_f32_16x16x32_bf16(a[i], b[j], acc[i][j], 0, 0, 0);
        }
        __syncthreads();
    }
#pragma unroll
    for (int i = 0; i < 4; ++i) {
        const int row = m0 + wm * 64 + i * 16 + quad * 4;
#pragma unroll
        for (int j = 0; j < 4; ++j) {
            const int cc = n0 + wn * 64 + j * 16 + col;
#pragma unroll
            for (int r = 0; r < 4; ++r) {
                float v = acc[i][j][r] * scale;
                if (cF32) ((float*)Cv)[(size_t)(row + r) * N + cc] = v;
                else      ((ushort_t*)Cv)[(size_t)(row + r) * N + cc] = f2bf(v);
            }
        }
    }
}

// ---- flash attention: round-6 LDS staging + no-max softmax.
// KV-tile 128, q-tile 64. No in-loop shuffles; 2 barriers per iteration. ----
__global__ __launch_bounds__(256) void attn_nomax(
    const ushort_t* __restrict__ Q, int ldq,
    const ushort_t* __restrict__ K, int ldk,
    const ushort_t* __restrict__ VT,
    const float* __restrict__ Mask,
    ushort_t* __restrict__ O, int ldo)
{
    __shared__ ushort_t Qs[64][72];
    __shared__ ushort_t Ks[128][72];   // [kv][s]
    __shared__ ushort_t Vs[64][136];   // [s][kv]
    __shared__ ushort_t Ps[64][72];    // [q][kv-local 64]

    const int t = threadIdx.x;
    const int lane = t & 63, wave = t >> 6;
    const int col = lane & 15, quad = lane >> 4;
    const int q0 = blockIdx.x * 64;
    const int h = blockIdx.y, n = blockIdx.z;

    {   // stage Q once
        const int r = t >> 2, c = (t & 3) * 16;
        const ushort_t* p = Q + (size_t)(n * T_SEQ + q0 + r) * ldq + h * 64 + c;
        *(uint4*)&Qs[r][c]     = *(const uint4*)p;
        *(uint4*)&Qs[r][c + 8] = *(const uint4*)(p + 8);
    }
    __syncthreads();
    const bf16x8 qa0 = *(const bf16x8*)&Qs[wave * 16 + col][quad * 8];
    const bf16x8 qa1 = *(const bf16x8*)&Qs[wave * 16 + col][32 + quad * 8];

    f32x4 o_acc[4];
#pragma unroll
    for (int i = 0; i < 4; ++i) o_acc[i] = (f32x4){0.f, 0.f, 0.f, 0.f};
    float l_run[4] = {0.f, 0.f, 0.f, 0.f};

    const float* Mrow = Mask + ((size_t)((n * 16 + h) * T_SEQ) + q0 + wave * 16 + quad * 4) * T_SEQ;

    for (int kt = 0; kt < T_SEQ / 128; ++kt) {
        const int kv0 = kt * 128;

        // mask prefetch (independent of staging; overlaps staging latency + barrier)
        float mk[8][4];
#pragma unroll
        for (int nt = 0; nt < 8; ++nt)
#pragma unroll
            for (int r = 0; r < 4; ++r)
                mk[nt][r] = Mrow[(size_t)r * T_SEQ + kv0 + nt * 16 + col];

        {   // stage K tile: 128 rows x 64 cols (coalesced)
            const int r = t >> 2, c = (t & 3) * 16;
#pragma unroll
            for (int p64 = 0; p64 < 128; p64 += 64) {
                const ushort_t* p = K + (size_t)(n * T_SEQ + kv0 + p64 + r) * ldk + h * 64 + c;
                *(uint4*)&Ks[p64 + r][c]     = *(const uint4*)p;
                *(uint4*)&Ks[p64 + r][c + 8] = *(const uint4*)(p + 8);
            }
        }
        {   // stage V^T tile: 64 s-rows x 128 kv-cols (coalesced)
            const int s = t >> 2, cb = (t & 3) * 32;
            const ushort_t* p = VT + ((size_t)(n * 16 + h) * 64 + s) * T_SEQ + kv0 + cb;
            *(uint4*)&Vs[s][cb]      = *(const uint4*)p;
            *(uint4*)&Vs[s][cb + 8]  = *(const uint4*)(p + 8);
            *(uint4*)&Vs[s][cb + 16] = *(const uint4*)(p + 16);
            *(uint4*)&Vs[s][cb + 24] = *(const uint4*)(p + 24);
        }
        __syncthreads();

        // S = Q.K^T over 128 kv cols; clamped mask-add
        f32x4 s_acc[8];
#pragma unroll
        for (int nt = 0; nt < 8; ++nt) {
            bf16x8 kb0 = *(const bf16x8*)&Ks[nt * 16 + col][quad * 8];
            bf16x8 kb1 = *(const bf16x8*)&Ks[nt * 16 + col][32 + quad * 8];
            f32x4 z = (f32x4){0.f, 0.f, 0.f, 0.f};
            z = __builtin_amdgcn_mfma_f32_16x16x32_bf16(qa0, kb0, z, 0, 0, 0);
            z = __builtin_amdgcn_mfma_f32_16x16x32_bf16(qa1, kb1, z, 0, 0, 0);
#pragma unroll
            for (int r = 0; r < 4; ++r)
                z[r] = fminf(z[r] - 1e9f * mk[nt][r], 60.f);   // clamp guards exp overflow
            s_acc[nt] = z;
        }
        // exp (no max subtraction) + per-lane partial row-sums
#pragma unroll
        for (int nt = 0; nt < 8; ++nt)
#pragma unroll
            for (int r = 0; r < 4; ++r) {
                float p = __expf(s_acc[nt][r]);
                s_acc[nt][r] = p;
                l_run[r] += p;
            }

        // PV in two 64-col chunks; Ps rows are wave-private -> no barrier
#pragma unroll
        for (int ch = 0; ch < 2; ++ch) {
#pragma unroll
            for (int nt = 0; nt < 4; ++nt)
#pragma unroll
                for (int r = 0; r < 4; ++r)
                    Ps[wave * 16 + quad * 4 + r][nt * 16 + col] = f2bf(s_acc[ch * 4 + nt][r]);
            bf16x8 pa0 = *(const bf16x8*)&Ps[wave * 16 + col][quad * 8];
            bf16x8 pa1 = *(const bf16x8*)&Ps[wave * 16 + col][32 + quad * 8];
#pragma unroll
            for (int st = 0; st < 4; ++st) {
                bf16x8 vb0 = *(const bf16x8*)&Vs[st * 16 + col][ch * 64 + quad * 8];
                bf16x8 vb1 = *(const bf16x8*)&Vs[st * 16 + col][ch * 64 + 32 + quad * 8];
                o_acc[st] = __builtin_amdgcn_mfma_f32_16x16x32_bf16(pa0, vb0, o_acc[st], 0, 0, 0);
                o_acc[st] = __builtin_amdgcn_mfma_f32_16x16x32_bf16(pa1, vb1, o_acc[st], 0, 0, 0);
            }
        }
        __syncthreads();
    }

    // epilogue: 16-lane row-sum reduction, normalize, store
#pragma unroll
    for (int r = 0; r < 4; ++r) {
        float l = l_run[r];
#pragma unroll
        for (int off = 1; off < 16; off <<= 1) l += __shfl_xor(l, off);
        float inv = 1.0f / (l + 1e-30f);
        int qrow = q0 + wave * 16 + quad * 4 + r;
        size_t base = (size_t)(n * T_SEQ + qrow) * ldo + h * 64;
#pragma unroll
        for (int st = 0; st < 4; ++st)
            O[base + st * 16 + col] = f2bf(o_acc[st][r] * inv);
    }
}

extern "C" void kernel_launch(void* const* d_in, const int* in_sizes, int n_in,
                              void* d_out, int out_size, void* d_ws, size_t ws_size,
                              hipStream_t stream) {
    const float* q_seqs = (const float*)d_in[0];
    const float* r_seqs = (const float*)d_in[1];
    const float* mask   = (const float*)d_in[2];
    const float* Wq     = (const float*)d_in[3];
    const float* Wk     = (const float*)d_in[4];
    const float* Wv     = (const float*)d_in[5];
    const float* Wo     = (const float*)d_in[6];

    const size_t R = 4194304;  // region stride in ushorts (8 MiB)
    ushort_t* ws = (ushort_t*)d_ws;
    ushort_t* bfQ  = ws;            // R0: q_seqs bf16; later reused as wsO
    ushort_t* bfR  = ws + R;        // R1: r_seqs bf16; later reused as wsVT
    ushort_t* WqT  = ws + 2 * R;    // R2: WqT | WkvT(2048 rows) | WoT
    ushort_t* WkvT = WqT + 1048576;
    ushort_t* WoT  = WqT + 3145728;
    ushort_t* wsQ  = ws + 3 * R;    // R3
    ushort_t* wsKV = ws + 4 * R;    // R4+R5: [4096][2048]
    ushort_t* wsVT = bfR;
    ushort_t* wsO  = bfQ;

    dim3 blk(256);

    hipLaunchKernelGGL(cvt_bf16_2, dim3(2048, 2), blk, 0, stream, q_seqs, r_seqs, bfQ, bfR);
    hipLaunchKernelGGL(cvt_w4, dim3(16, 16, 4), blk, 0, stream,
                       Wq, Wk, Wv, Wo, WqT, WkvT, WkvT + 1048576, WoT);

    hipLaunchKernelGGL(gemm128, dim3(8, 32), blk, 0, stream,
                       bfQ, WqT, (void*)wsQ, 4096, 1024, 1024, 0.125f, 0);
    hipLaunchKernelGGL(gemm128, dim3(16, 32), blk, 0, stream,
                       bfR, WkvT, (void*)wsKV, 4096, 2048, 1024, 1.0f, 0);

    hipLaunchKernelGGL(transpose_v, dim3(32, 16, 2), blk, 0, stream,
                       wsKV + 1024, 2048, wsVT);

    hipLaunchKernelGGL(attn_nomax, dim3(32, 16, 2), blk, 0, stream,
                       wsQ, 1024, wsKV, 2048, wsVT, mask, wsO, 1024);

    hipLaunchKernelGGL(gemm128, dim3(8, 32), blk, 0, stream,
                       wsO, WoT, d_out, 4096, 1024, 1024, 1.0f, 1);
}

// Round 9
// 921.233 us; speedup vs baseline: 1.1585x; 1.0935x over previous
//
#include <hip/hip_runtime.h>

typedef unsigned short ushort_t;
typedef __attribute__((ext_vector_type(8))) short bf16x8;   // 8 bf16 = 4 VGPRs
typedef __attribute__((ext_vector_type(4))) float f32x4;

#define T_SEQ 2048

__device__ __forceinline__ ushort_t f2bf(float f) {
    unsigned u = __float_as_uint(f);
    unsigned r = u + 0x7FFFu + ((u >> 16) & 1u);
    return (ushort_t)(r >> 16);
}
__device__ __forceinline__ unsigned pack2(float a, float b) {
    return (unsigned)f2bf(a) | ((unsigned)f2bf(b) << 16);
}
// cheap round-to-nearest (no tie-to-even): 2 VALU ops
__device__ __forceinline__ ushort_t f2bf_fast(float f) {
    return (ushort_t)((__float_as_uint(f) + 0x8000u) >> 16);
}

// ---- fp32 -> bf16 for both activation tensors (blockIdx.y selects) ----
__global__ __launch_bounds__(256) void cvt_bf16_2(const float* __restrict__ a,
                                                  const float* __restrict__ b,
                                                  ushort_t* __restrict__ oa,
                                                  ushort_t* __restrict__ ob) {
    const float* in = blockIdx.y ? b : a;
    ushort_t* out = blockIdx.y ? ob : oa;
    size_t i = ((size_t)blockIdx.x * 256 + threadIdx.x) * 8;
    float4 f0 = *(const float4*)(in + i);
    float4 f1 = *(const float4*)(in + i + 4);
    uint4 w;
    w.x = pack2(f0.x, f0.y); w.y = pack2(f0.z, f0.w);
    w.z = pack2(f1.x, f1.y); w.w = pack2(f1.z, f1.w);
    *(uint4*)(out + i) = w;
}

// ---- all 4 weights: fp32 [k][n] -> bf16 transposed out[n][k] (blockIdx.z selects) ----
__global__ __launch_bounds__(256) void cvt_w4(
    const float* __restrict__ W0, const float* __restrict__ W1,
    const float* __restrict__ W2, const float* __restrict__ W3,
    ushort_t* __restrict__ O0, ushort_t* __restrict__ O1,
    ushort_t* __restrict__ O2, ushort_t* __restrict__ O3) {
    __shared__ ushort_t Ls[64][72];
    const int z = blockIdx.z;
    const float* W = (z == 0) ? W0 : (z == 1) ? W1 : (z == 2) ? W2 : W3;
    ushort_t* out  = (z == 0) ? O0 : (z == 1) ? O1 : (z == 2) ? O2 : O3;
    const int t = threadIdx.x;
    const int k0 = blockIdx.y * 64, n0 = blockIdx.x * 64;
    {
        const int r = t >> 2, c = (t & 3) * 16;
        const float* p = W + (size_t)(k0 + r) * 1024 + n0 + c;
        float4 a = *(const float4*)p, b = *(const float4*)(p + 4);
        float4 c2 = *(const float4*)(p + 8), d = *(const float4*)(p + 12);
        uint4 w0, w1;
        w0.x = pack2(a.x, a.y); w0.y = pack2(a.z, a.w);
        w0.z = pack2(b.x, b.y); w0.w = pack2(b.z, b.w);
        w1.x = pack2(c2.x, c2.y); w1.y = pack2(c2.z, c2.w);
        w1.z = pack2(d.x, d.y); w1.w = pack2(d.z, d.w);
        *(uint4*)&Ls[r][c] = w0;
        *(uint4*)&Ls[r][c + 8] = w1;
    }
    __syncthreads();
    {
        const int nn = t >> 2, kc = (t & 3) * 16;
        unsigned u[8];
#pragma unroll
        for (int a2 = 0; a2 < 8; ++a2)
            u[a2] = (unsigned)Ls[kc + 2 * a2][nn] | ((unsigned)Ls[kc + 2 * a2 + 1][nn] << 16);
        uint4 w0 = {u[0], u[1], u[2], u[3]}, w1 = {u[4], u[5], u[6], u[7]};
        ushort_t* op = out + (size_t)(n0 + nn) * 1024 + k0 + kc;
        *(uint4*)op = w0;
        *(uint4*)(op + 8) = w1;
    }
}

// ---- V bf16 [b*2048+t][ldin] -> VT [((b*16+h)*64+s)][2048] ----
__global__ __launch_bounds__(256) void transpose_v(const ushort_t* __restrict__ Vin, int ldin,
                                                   ushort_t* __restrict__ VT) {
    __shared__ ushort_t Ls[64][72];
    const int t = threadIdx.x;
    const int t0 = blockIdx.x * 64;
    const int h = blockIdx.y, b = blockIdx.z;
    {
        const int r = t >> 2, c = (t & 3) * 16;
        const ushort_t* p = Vin + (size_t)(b * T_SEQ + t0 + r) * ldin + h * 64 + c;
        *(uint4*)&Ls[r][c] = *(const uint4*)p;
        *(uint4*)&Ls[r][c + 8] = *(const uint4*)(p + 8);
    }
    __syncthreads();
    {
        const int s = t >> 2, tc = (t & 3) * 16;
        unsigned u[8];
#pragma unroll
        for (int a2 = 0; a2 < 8; ++a2)
            u[a2] = (unsigned)Ls[tc + 2 * a2][s] | ((unsigned)Ls[tc + 2 * a2 + 1][s] << 16);
        uint4 w0 = {u[0], u[1], u[2], u[3]}, w1 = {u[4], u[5], u[6], u[7]};
        ushort_t* op = VT + ((size_t)(b * 16 + h) * 64 + s) * T_SEQ + t0 + tc;
        *(uint4*)op = w0;
        *(uint4*)(op + 8) = w1;
    }
}

// ---- core GEMM tile body: C = scale * A[M,K] * Bt[N,K]^T, 128x128, BK=64,
// plain vector staging (round-6 validated; no register prefetch). ----
__device__ __forceinline__ void gemm_tile(
    const ushort_t* __restrict__ A, const ushort_t* __restrict__ Bt,
    void* __restrict__ Cv, int N, int K, float scale, int cF32,
    int m0, int n0, ushort_t (*As)[64], ushort_t (*Bs)[64])
{
    const int t = threadIdx.x;
    const int lane = t & 63, wave = t >> 6;
    const int col = lane & 15, quad = lane >> 4;
    const int wm = wave & 1, wn = wave >> 1;

    f32x4 acc[4][4];
#pragma unroll
    for (int i = 0; i < 4; ++i)
#pragma unroll
        for (int j = 0; j < 4; ++j) acc[i][j] = (f32x4){0.f, 0.f, 0.f, 0.f};

    for (int k0 = 0; k0 < K; k0 += 64) {
#pragma unroll
        for (int j = 0; j < 4; ++j) {
            const int c = j * 256 + t;
            const int row = c >> 3, cc = (c & 7) * 8;
            *(uint4*)&As[row][cc] = *(const uint4*)(A + (size_t)(m0 + row) * K + k0 + cc);
            *(uint4*)&Bs[row][cc] = *(const uint4*)(Bt + (size_t)(n0 + row) * K + k0 + cc);
        }
        __syncthreads();
#pragma unroll
        for (int kk = 0; kk < 2; ++kk) {
            bf16x8 a[4], b[4];
#pragma unroll
            for (int i = 0; i < 4; ++i)
                a[i] = *(const bf16x8*)&As[wm * 64 + i * 16 + col][kk * 32 + quad * 8];
#pragma unroll
            for (int j = 0; j < 4; ++j)
                b[j] = *(const bf16x8*)&Bs[wn * 64 + j * 16 + col][kk * 32 + quad * 8];
#pragma unroll
            for (int i = 0; i < 4; ++i)
#pragma unroll
                for (int j = 0; j < 4; ++j)
                    acc[i][j] = __builtin_amdgcn_mfma_f32_16x16x32_bf16(a[i], b[j], acc[i][j], 0, 0, 0);
        }
        __syncthreads();
    }
#pragma unroll
    for (int i = 0; i < 4; ++i) {
        const int row = m0 + wm * 64 + i * 16 + quad * 4;
#pragma unroll
        for (int j = 0; j < 4; ++j) {
            const int cc = n0 + wn * 64 + j * 16 + col;
#pragma unroll
            for (int r = 0; r < 4; ++r) {
                float v = acc[i][j][r] * scale;
                if (cF32) ((float*)Cv)[(size_t)(row + r) * N + cc] = v;
                else      ((ushort_t*)Cv)[(size_t)(row + r) * N + cc] = f2bf(v);
            }
        }
    }
}

// ---- fused Q + KV projection: grid (24, 32). bx<8 -> Q proj, else KV proj. ----
__global__ __launch_bounds__(256) void gemm_proj(
    const ushort_t* __restrict__ Aq, const ushort_t* __restrict__ WqT,
    ushort_t* __restrict__ Cq,
    const ushort_t* __restrict__ Akv, const ushort_t* __restrict__ WkvT,
    ushort_t* __restrict__ Ckv)
{
    __shared__ ushort_t As[128][64];
    __shared__ ushort_t Bs[128][64];
    const int bx = blockIdx.x;
    const bool isQ = bx < 8;
    const ushort_t* A  = isQ ? Aq : Akv;
    const ushort_t* Bt = isQ ? WqT : WkvT;
    ushort_t* C        = isQ ? Cq : Ckv;
    const int N        = isQ ? 1024 : 2048;
    const int n0       = (isQ ? bx : bx - 8) * 128;
    const float scale  = isQ ? 0.125f : 1.0f;
    gemm_tile(A, Bt, (void*)C, N, 1024, scale, 0, blockIdx.y * 128, n0, As, Bs);
}

// ---- standalone GEMM (output projection) ----
__global__ __launch_bounds__(256) void gemm128(
    const ushort_t* __restrict__ A, const ushort_t* __restrict__ Bt,
    void* __restrict__ Cv, int M, int N, int K, float scale, int cF32)
{
    __shared__ ushort_t As[128][64];
    __shared__ ushort_t Bs[128][64];
    gemm_tile(A, Bt, Cv, N, K, scale, cF32, blockIdx.y * 128, blockIdx.x * 128, As, Bs);
}

// ---- flash attention: LDS staging + no-max softmax; Qs/Ps aliased (44 KB LDS,
// 3 blocks/CU); cheap bf16 pack for Ps. KV-tile 128, 2 barriers/iter. ----
__global__ __launch_bounds__(256) void attn_nomax(
    const ushort_t* __restrict__ Q, int ldq,
    const ushort_t* __restrict__ K, int ldk,
    const ushort_t* __restrict__ VT,
    const float* __restrict__ Mask,
    ushort_t* __restrict__ O, int ldo)
{
    __shared__ ushort_t PQ[64][72];    // Qs in prologue, Ps inside the loop
    __shared__ ushort_t Ks[128][72];   // [kv][s]
    __shared__ ushort_t Vs[64][136];   // [s][kv]

    const int t = threadIdx.x;
    const int lane = t & 63, wave = t >> 6;
    const int col = lane & 15, quad = lane >> 4;
    const int q0 = blockIdx.x * 64;
    const int h = blockIdx.y, n = blockIdx.z;

    {   // stage Q once (into PQ, freed after frag load)
        const int r = t >> 2, c = (t & 3) * 16;
        const ushort_t* p = Q + (size_t)(n * T_SEQ + q0 + r) * ldq + h * 64 + c;
        *(uint4*)&PQ[r][c]     = *(const uint4*)p;
        *(uint4*)&PQ[r][c + 8] = *(const uint4*)(p + 8);
    }
    __syncthreads();
    const bf16x8 qa0 = *(const bf16x8*)&PQ[wave * 16 + col][quad * 8];
    const bf16x8 qa1 = *(const bf16x8*)&PQ[wave * 16 + col][32 + quad * 8];
    // NOTE: PQ is reused as Ps below. Safe: the first Ps write happens after the
    // staging __syncthreads of iteration 0, by which point every wave has
    // executed its Q-frag loads (they precede that barrier in program order).

    f32x4 o_acc[4];
#pragma unroll
    for (int i = 0; i < 4; ++i) o_acc[i] = (f32x4){0.f, 0.f, 0.f, 0.f};
    float l_run[4] = {0.f, 0.f, 0.f, 0.f};

    const float* Mrow = Mask + ((size_t)((n * 16 + h) * T_SEQ) + q0 + wave * 16 + quad * 4) * T_SEQ;

    for (int kt = 0; kt < T_SEQ / 128; ++kt) {
        const int kv0 = kt * 128;

        // mask prefetch (independent of staging; overlaps staging latency + barrier)
        float mk[8][4];
#pragma unroll
        for (int nt = 0; nt < 8; ++nt)
#pragma unroll
            for (int r = 0; r < 4; ++r)
                mk[nt][r] = Mrow[(size_t)r * T_SEQ + kv0 + nt * 16 + col];

        {   // stage K tile: 128 rows x 64 cols (coalesced)
            const int r = t >> 2, c = (t & 3) * 16;
#pragma unroll
            for (int p64 = 0; p64 < 128; p64 += 64) {
                const ushort_t* p = K + (size_t)(n * T_SEQ + kv0 + p64 + r) * ldk + h * 64 + c;
                *(uint4*)&Ks[p64 + r][c]     = *(const uint4*)p;
                *(uint4*)&Ks[p64 + r][c + 8] = *(const uint4*)(p + 8);
            }
        }
        {   // stage V^T tile: 64 s-rows x 128 kv-cols (coalesced)
            const int s = t >> 2, cb = (t & 3) * 32;
            const ushort_t* p = VT + ((size_t)(n * 16 + h) * 64 + s) * T_SEQ + kv0 + cb;
            *(uint4*)&Vs[s][cb]      = *(const uint4*)p;
            *(uint4*)&Vs[s][cb + 8]  = *(const uint4*)(p + 8);
            *(uint4*)&Vs[s][cb + 16] = *(const uint4*)(p + 16);
            *(uint4*)&Vs[s][cb + 24] = *(const uint4*)(p + 24);
        }
        __syncthreads();

        // S = Q.K^T over 128 kv cols; clamped mask-add
        f32x4 s_acc[8];
#pragma unroll
        for (int nt = 0; nt < 8; ++nt) {
            bf16x8 kb0 = *(const bf16x8*)&Ks[nt * 16 + col][quad * 8];
            bf16x8 kb1 = *(const bf16x8*)&Ks[nt * 16 + col][32 + quad * 8];
            f32x4 z = (f32x4){0.f, 0.f, 0.f, 0.f};
            z = __builtin_amdgcn_mfma_f32_16x16x32_bf16(qa0, kb0, z, 0, 0, 0);
            z = __builtin_amdgcn_mfma_f32_16x16x32_bf16(qa1, kb1, z, 0, 0, 0);
#pragma unroll
            for (int r = 0; r < 4; ++r)
                z[r] = fminf(z[r] - 1e9f * mk[nt][r], 60.f);   // clamp guards exp overflow
            s_acc[nt] = z;
        }
        // exp (no max subtraction) + per-lane partial row-sums
#pragma unroll
        for (int nt = 0; nt < 8; ++nt)
#pragma unroll
            for (int r = 0; r < 4; ++r) {
                float p = __expf(s_acc[nt][r]);
                s_acc[nt][r] = p;
                l_run[r] += p;
            }

        // PV in two 64-col chunks; Ps (=PQ) rows are wave-private -> no barrier
#pragma unroll
        for (int ch = 0; ch < 2; ++ch) {
#pragma unroll
            for (int nt = 0; nt < 4; ++nt)
#pragma unroll
                for (int r = 0; r < 4; ++r)
                    PQ[wave * 16 + quad * 4 + r][nt * 16 + col] = f2bf_fast(s_acc[ch * 4 + nt][r]);
            bf16x8 pa0 = *(const bf16x8*)&PQ[wave * 16 + col][quad * 8];
            bf16x8 pa1 = *(const bf16x8*)&PQ[wave * 16 + col][32 + quad * 8];
#pragma unroll
            for (int st = 0; st < 4; ++st) {
                bf16x8 vb0 = *(const bf16x8*)&Vs[st * 16 + col][ch * 64 + quad * 8];
                bf16x8 vb1 = *(const bf16x8*)&Vs[st * 16 + col][ch * 64 + 32 + quad * 8];
                o_acc[st] = __builtin_amdgcn_mfma_f32_16x16x32_bf16(pa0, vb0, o_acc[st], 0, 0, 0);
                o_acc[st] = __builtin_amdgcn_mfma_f32_16x16x32_bf16(pa1, vb1, o_acc[st], 0, 0, 0);
            }
        }
        __syncthreads();
    }

    // epilogue: 16-lane row-sum reduction, normalize, store
#pragma unroll
    for (int r = 0; r < 4; ++r) {
        float l = l_run[r];
#pragma unroll
        for (int off = 1; off < 16; off <<= 1) l += __shfl_xor(l, off);
        float inv = 1.0f / (l + 1e-30f);
        int qrow = q0 + wave * 16 + quad * 4 + r;
        size_t base = (size_t)(n * T_SEQ + qrow) * ldo + h * 64;
#pragma unroll
        for (int st = 0; st < 4; ++st)
            O[base + st * 16 + col] = f2bf(o_acc[st][r] * inv);
    }
}

extern "C" void kernel_launch(void* const* d_in, const int* in_sizes, int n_in,
                              void* d_out, int out_size, void* d_ws, size_t ws_size,
                              hipStream_t stream) {
    const float* q_seqs = (const float*)d_in[0];
    const float* r_seqs = (const float*)d_in[1];
    const float* mask   = (const float*)d_in[2];
    const float* Wq     = (const float*)d_in[3];
    const float* Wk     = (const float*)d_in[4];
    const float* Wv     = (const float*)d_in[5];
    const float* Wo     = (const float*)d_in[6];

    const size_t R = 4194304;  // region stride in ushorts (8 MiB)
    ushort_t* ws = (ushort_t*)d_ws;
    ushort_t* bfQ  = ws;            // R0: q_seqs bf16; later reused as wsO
    ushort_t* bfR  = ws + R;        // R1: r_seqs bf16; later reused as wsVT
    ushort_t* WqT  = ws + 2 * R;    // R2: WqT | WkvT(2048 rows) | WoT
    ushort_t* WkvT = WqT + 1048576;
    ushort_t* WoT  = WqT + 3145728;
    ushort_t* wsQ  = ws + 3 * R;    // R3
    ushort_t* wsKV = ws + 4 * R;    // R4+R5: [4096][2048]
    ushort_t* wsVT = bfR;
    ushort_t* wsO  = bfQ;

    dim3 blk(256);

    hipLaunchKernelGGL(cvt_bf16_2, dim3(2048, 2), blk, 0, stream, q_seqs, r_seqs, bfQ, bfR);
    hipLaunchKernelGGL(cvt_w4, dim3(16, 16, 4), blk, 0, stream,
                       Wq, Wk, Wv, Wo, WqT, WkvT, WkvT + 1048576, WoT);

    // fused Q + KV projection (768 blocks = 3/CU)
    hipLaunchKernelGGL(gemm_proj, dim3(24, 32), blk, 0, stream,
                       bfQ, WqT, wsQ, bfR, WkvT, wsKV);

    hipLaunchKernelGGL(transpose_v, dim3(32, 16, 2), blk, 0, stream,
                       wsKV + 1024, 2048, wsVT);

    hipLaunchKernelGGL(attn_nomax, dim3(32, 16, 2), blk, 0, stream,
                       wsQ, 1024, wsKV, 2048, wsVT, mask, wsO, 1024);

    hipLaunchKernelGGL(gemm128, dim3(8, 32), blk, 0, stream,
                       wsO, WoT, d_out, 4096, 1024, 1024, 1.0f, 1);
}

// Round 10
// 823.815 us; speedup vs baseline: 1.2954x; 1.1183x over previous
//
#include <hip/hip_runtime.h>

typedef unsigned short ushort_t;
typedef __attribute__((ext_vector_type(8))) short bf16x8;   // 8 bf16 = 4 VGPRs
typedef __attribute__((ext_vector_type(4))) float f32x4;

#define T_SEQ 2048

__device__ __forceinline__ ushort_t f2bf(float f) {
    unsigned u = __float_as_uint(f);
    unsigned r = u + 0x7FFFu + ((u >> 16) & 1u);
    return (ushort_t)(r >> 16);
}
__device__ __forceinline__ unsigned pack2(float a, float b) {
    return (unsigned)f2bf(a) | ((unsigned)f2bf(b) << 16);
}
// cheap round-to-nearest (no tie-to-even): 2 VALU ops
__device__ __forceinline__ ushort_t f2bf_fast(float f) {
    return (ushort_t)((__float_as_uint(f) + 0x8000u) >> 16);
}

// ---- fp32 -> bf16 for both activation tensors (blockIdx.y selects) ----
__global__ __launch_bounds__(256) void cvt_bf16_2(const float* __restrict__ a,
                                                  const float* __restrict__ b,
                                                  ushort_t* __restrict__ oa,
                                                  ushort_t* __restrict__ ob) {
    const float* in = blockIdx.y ? b : a;
    ushort_t* out = blockIdx.y ? ob : oa;
    size_t i = ((size_t)blockIdx.x * 256 + threadIdx.x) * 8;
    float4 f0 = *(const float4*)(in + i);
    float4 f1 = *(const float4*)(in + i + 4);
    uint4 w;
    w.x = pack2(f0.x, f0.y); w.y = pack2(f0.z, f0.w);
    w.z = pack2(f1.x, f1.y); w.w = pack2(f1.z, f1.w);
    *(uint4*)(out + i) = w;
}

// ---- all 4 weights: fp32 [k][n] -> bf16 transposed out[n][k] (blockIdx.z selects) ----
__global__ __launch_bounds__(256) void cvt_w4(
    const float* __restrict__ W0, const float* __restrict__ W1,
    const float* __restrict__ W2, const float* __restrict__ W3,
    ushort_t* __restrict__ O0, ushort_t* __restrict__ O1,
    ushort_t* __restrict__ O2, ushort_t* __restrict__ O3) {
    __shared__ ushort_t Ls[64][72];
    const int z = blockIdx.z;
    const float* W = (z == 0) ? W0 : (z == 1) ? W1 : (z == 2) ? W2 : W3;
    ushort_t* out  = (z == 0) ? O0 : (z == 1) ? O1 : (z == 2) ? O2 : O3;
    const int t = threadIdx.x;
    const int k0 = blockIdx.y * 64, n0 = blockIdx.x * 64;
    {
        const int r = t >> 2, c = (t & 3) * 16;
        const float* p = W + (size_t)(k0 + r) * 1024 + n0 + c;
        float4 a = *(const float4*)p, b = *(const float4*)(p + 4);
        float4 c2 = *(const float4*)(p + 8), d = *(const float4*)(p + 12);
        uint4 w0, w1;
        w0.x = pack2(a.x, a.y); w0.y = pack2(a.z, a.w);
        w0.z = pack2(b.x, b.y); w0.w = pack2(b.z, b.w);
        w1.x = pack2(c2.x, c2.y); w1.y = pack2(c2.z, c2.w);
        w1.z = pack2(d.x, d.y); w1.w = pack2(d.z, d.w);
        *(uint4*)&Ls[r][c] = w0;
        *(uint4*)&Ls[r][c + 8] = w1;
    }
    __syncthreads();
    {
        const int nn = t >> 2, kc = (t & 3) * 16;
        unsigned u[8];
#pragma unroll
        for (int a2 = 0; a2 < 8; ++a2)
            u[a2] = (unsigned)Ls[kc + 2 * a2][nn] | ((unsigned)Ls[kc + 2 * a2 + 1][nn] << 16);
        uint4 w0 = {u[0], u[1], u[2], u[3]}, w1 = {u[4], u[5], u[6], u[7]};
        ushort_t* op = out + (size_t)(n0 + nn) * 1024 + k0 + kc;
        *(uint4*)op = w0;
        *(uint4*)(op + 8) = w1;
    }
}

// ---- V bf16 [b*2048+t][ldin] -> VT [((b*16+h)*64+s)][2048] ----
__global__ __launch_bounds__(256) void transpose_v(const ushort_t* __restrict__ Vin, int ldin,
                                                   ushort_t* __restrict__ VT) {
    __shared__ ushort_t Ls[64][72];
    const int t = threadIdx.x;
    const int t0 = blockIdx.x * 64;
    const int h = blockIdx.y, b = blockIdx.z;
    {
        const int r = t >> 2, c = (t & 3) * 16;
        const ushort_t* p = Vin + (size_t)(b * T_SEQ + t0 + r) * ldin + h * 64 + c;
        *(uint4*)&Ls[r][c] = *(const uint4*)p;
        *(uint4*)&Ls[r][c + 8] = *(const uint4*)(p + 8);
    }
    __syncthreads();
    {
        const int s = t >> 2, tc = (t & 3) * 16;
        unsigned u[8];
#pragma unroll
        for (int a2 = 0; a2 < 8; ++a2)
            u[a2] = (unsigned)Ls[tc + 2 * a2][s] | ((unsigned)Ls[tc + 2 * a2 + 1][s] << 16);
        uint4 w0 = {u[0], u[1], u[2], u[3]}, w1 = {u[4], u[5], u[6], u[7]};
        ushort_t* op = VT + ((size_t)(b * 16 + h) * 64 + s) * T_SEQ + t0 + tc;
        *(uint4*)op = w0;
        *(uint4*)(op + 8) = w1;
    }
}

// ---- core GEMM tile body: C = scale * A[M,K] * Bt[N,K]^T, 128x128, BK=64,
// plain vector staging (round-6 validated). ----
__device__ __forceinline__ void gemm_tile(
    const ushort_t* __restrict__ A, const ushort_t* __restrict__ Bt,
    void* __restrict__ Cv, int N, int K, float scale, int cF32,
    int m0, int n0, ushort_t (*As)[64], ushort_t (*Bs)[64])
{
    const int t = threadIdx.x;
    const int lane = t & 63, wave = t >> 6;
    const int col = lane & 15, quad = lane >> 4;
    const int wm = wave & 1, wn = wave >> 1;

    f32x4 acc[4][4];
#pragma unroll
    for (int i = 0; i < 4; ++i)
#pragma unroll
        for (int j = 0; j < 4; ++j) acc[i][j] = (f32x4){0.f, 0.f, 0.f, 0.f};

    for (int k0 = 0; k0 < K; k0 += 64) {
#pragma unroll
        for (int j = 0; j < 4; ++j) {
            const int c = j * 256 + t;
            const int row = c >> 3, cc = (c & 7) * 8;
            *(uint4*)&As[row][cc] = *(const uint4*)(A + (size_t)(m0 + row) * K + k0 + cc);
            *(uint4*)&Bs[row][cc] = *(const uint4*)(Bt + (size_t)(n0 + row) * K + k0 + cc);
        }
        __syncthreads();
#pragma unroll
        for (int kk = 0; kk < 2; ++kk) {
            bf16x8 a[4], b[4];
#pragma unroll
            for (int i = 0; i < 4; ++i)
                a[i] = *(const bf16x8*)&As[wm * 64 + i * 16 + col][kk * 32 + quad * 8];
#pragma unroll
            for (int j = 0; j < 4; ++j)
                b[j] = *(const bf16x8*)&Bs[wn * 64 + j * 16 + col][kk * 32 + quad * 8];
#pragma unroll
            for (int i = 0; i < 4; ++i)
#pragma unroll
                for (int j = 0; j < 4; ++j)
                    acc[i][j] = __builtin_amdgcn_mfma_f32_16x16x32_bf16(a[i], b[j], acc[i][j], 0, 0, 0);
        }
        __syncthreads();
    }
#pragma unroll
    for (int i = 0; i < 4; ++i) {
        const int row = m0 + wm * 64 + i * 16 + quad * 4;
#pragma unroll
        for (int j = 0; j < 4; ++j) {
            const int cc = n0 + wn * 64 + j * 16 + col;
#pragma unroll
            for (int r = 0; r < 4; ++r) {
                float v = acc[i][j][r] * scale;
                if (cF32) ((float*)Cv)[(size_t)(row + r) * N + cc] = v;
                else      ((ushort_t*)Cv)[(size_t)(row + r) * N + cc] = f2bf(v);
            }
        }
    }
}

// ---- fused Q + KV projection: grid (24, 32). bx<8 -> Q proj, else KV proj. ----
__global__ __launch_bounds__(256) void gemm_proj(
    const ushort_t* __restrict__ Aq, const ushort_t* __restrict__ WqT,
    ushort_t* __restrict__ Cq,
    const ushort_t* __restrict__ Akv, const ushort_t* __restrict__ WkvT,
    ushort_t* __restrict__ Ckv)
{
    __shared__ ushort_t As[128][64];
    __shared__ ushort_t Bs[128][64];
    const int bx = blockIdx.x;
    const bool isQ = bx < 8;
    const ushort_t* A  = isQ ? Aq : Akv;
    const ushort_t* Bt = isQ ? WqT : WkvT;
    ushort_t* C        = isQ ? Cq : Ckv;
    const int N        = isQ ? 1024 : 2048;
    const int n0       = (isQ ? bx : bx - 8) * 128;
    const float scale  = isQ ? 0.125f : 1.0f;
    gemm_tile(A, Bt, (void*)C, N, 1024, scale, 0, blockIdx.y * 128, n0, As, Bs);
}

// ---- standalone GEMM (output projection) ----
__global__ __launch_bounds__(256) void gemm128(
    const ushort_t* __restrict__ A, const ushort_t* __restrict__ Bt,
    void* __restrict__ Cv, int M, int N, int K, float scale, int cF32)
{
    __shared__ ushort_t As[128][64];
    __shared__ ushort_t Bs[128][64];
    gemm_tile(A, Bt, Cv, N, K, scale, cF32, blockIdx.y * 128, blockIdx.x * 128, As, Bs);
}

// ---- flash attention: q-tile 128 (512 thr, 8 waves), KV-tile 128.
// Halves K/V L3 re-read traffic vs q-tile 64. No-max softmax, Qs/Ps aliased. ----
__global__ __launch_bounds__(512) void attn_nomax(
    const ushort_t* __restrict__ Q, int ldq,
    const ushort_t* __restrict__ K, int ldk,
    const ushort_t* __restrict__ VT,
    const float* __restrict__ Mask,
    ushort_t* __restrict__ O, int ldo)
{
    __shared__ ushort_t PQ[128][72];   // Qs in prologue, Ps inside the loop
    __shared__ ushort_t Ks[128][72];   // [kv][s]
    __shared__ ushort_t Vs[64][136];   // [s][kv]

    const int t = threadIdx.x;
    const int lane = t & 63, wave = t >> 6;      // wave 0..7 -> q-strip
    const int col = lane & 15, quad = lane >> 4;
    const int q0 = blockIdx.x * 128;
    const int h = blockIdx.y, n = blockIdx.z;

    {   // stage Q once: 128 rows x 64 cols, 4 thr/row x 2 uint4
        const int r = t >> 2, c = (t & 3) * 16;
        const ushort_t* p = Q + (size_t)(n * T_SEQ + q0 + r) * ldq + h * 64 + c;
        *(uint4*)&PQ[r][c]     = *(const uint4*)p;
        *(uint4*)&PQ[r][c + 8] = *(const uint4*)(p + 8);
    }
    __syncthreads();
    const bf16x8 qa0 = *(const bf16x8*)&PQ[wave * 16 + col][quad * 8];
    const bf16x8 qa1 = *(const bf16x8*)&PQ[wave * 16 + col][32 + quad * 8];
    // PQ reused as Ps below: every wave's Q-frag ds_reads complete before the
    // iteration-0 staging __syncthreads (lgkmcnt(0) drained at barrier).

    f32x4 o_acc[4];
#pragma unroll
    for (int i = 0; i < 4; ++i) o_acc[i] = (f32x4){0.f, 0.f, 0.f, 0.f};
    float l_run[4] = {0.f, 0.f, 0.f, 0.f};

    const float* Mrow = Mask + ((size_t)((n * 16 + h) * T_SEQ) + q0 + wave * 16 + quad * 4) * T_SEQ;

    for (int kt = 0; kt < T_SEQ / 128; ++kt) {
        const int kv0 = kt * 128;

        // mask prefetch (independent of staging; overlaps staging latency + barrier)
        float mk[8][4];
#pragma unroll
        for (int nt = 0; nt < 8; ++nt)
#pragma unroll
            for (int r = 0; r < 4; ++r)
                mk[nt][r] = Mrow[(size_t)r * T_SEQ + kv0 + nt * 16 + col];

        {   // stage K tile: 128 rows x 64 cols, single pass with 512 thr
            const int r = t >> 2, c = (t & 3) * 16;
            const ushort_t* p = K + (size_t)(n * T_SEQ + kv0 + r) * ldk + h * 64 + c;
            *(uint4*)&Ks[r][c]     = *(const uint4*)p;
            *(uint4*)&Ks[r][c + 8] = *(const uint4*)(p + 8);
        }
        {   // stage V^T tile: 64 s-rows x 128 kv-cols, 8 thr/row x 2 uint4
            const int s = t >> 3, cb = (t & 7) * 16;
            const ushort_t* p = VT + ((size_t)(n * 16 + h) * 64 + s) * T_SEQ + kv0 + cb;
            *(uint4*)&Vs[s][cb]     = *(const uint4*)p;
            *(uint4*)&Vs[s][cb + 8] = *(const uint4*)(p + 8);
        }
        __syncthreads();

        // S = Q.K^T over 128 kv cols; clamped mask-add
        f32x4 s_acc[8];
#pragma unroll
        for (int nt = 0; nt < 8; ++nt) {
            bf16x8 kb0 = *(const bf16x8*)&Ks[nt * 16 + col][quad * 8];
            bf16x8 kb1 = *(const bf16x8*)&Ks[nt * 16 + col][32 + quad * 8];
            f32x4 z = (f32x4){0.f, 0.f, 0.f, 0.f};
            z = __builtin_amdgcn_mfma_f32_16x16x32_bf16(qa0, kb0, z, 0, 0, 0);
            z = __builtin_amdgcn_mfma_f32_16x16x32_bf16(qa1, kb1, z, 0, 0, 0);
#pragma unroll
            for (int r = 0; r < 4; ++r)
                z[r] = fminf(z[r] - 1e9f * mk[nt][r], 60.f);   // clamp guards exp overflow
            s_acc[nt] = z;
        }
        // exp (no max subtraction) + per-lane partial row-sums
#pragma unroll
        for (int nt = 0; nt < 8; ++nt)
#pragma unroll
            for (int r = 0; r < 4; ++r) {
                float p = __expf(s_acc[nt][r]);
                s_acc[nt][r] = p;
                l_run[r] += p;
            }

        // PV in two 64-col chunks; Ps (=PQ) rows are wave-private -> no barrier
#pragma unroll
        for (int ch = 0; ch < 2; ++ch) {
#pragma unroll
            for (int nt = 0; nt < 4; ++nt)
#pragma unroll
                for (int r = 0; r < 4; ++r)
                    PQ[wave * 16 + quad * 4 + r][nt * 16 + col] = f2bf_fast(s_acc[ch * 4 + nt][r]);
            bf16x8 pa0 = *(const bf16x8*)&PQ[wave * 16 + col][quad * 8];
            bf16x8 pa1 = *(const bf16x8*)&PQ[wave * 16 + col][32 + quad * 8];
#pragma unroll
            for (int st = 0; st < 4; ++st) {
                bf16x8 vb0 = *(const bf16x8*)&Vs[st * 16 + col][ch * 64 + quad * 8];
                bf16x8 vb1 = *(const bf16x8*)&Vs[st * 16 + col][ch * 64 + 32 + quad * 8];
                o_acc[st] = __builtin_amdgcn_mfma_f32_16x16x32_bf16(pa0, vb0, o_acc[st], 0, 0, 0);
                o_acc[st] = __builtin_amdgcn_mfma_f32_16x16x32_bf16(pa1, vb1, o_acc[st], 0, 0, 0);
            }
        }
        __syncthreads();
    }

    // epilogue: 16-lane row-sum reduction, normalize, store
#pragma unroll
    for (int r = 0; r < 4; ++r) {
        float l = l_run[r];
#pragma unroll
        for (int off = 1; off < 16; off <<= 1) l += __shfl_xor(l, off);
        float inv = 1.0f / (l + 1e-30f);
        int qrow = q0 + wave * 16 + quad * 4 + r;
        size_t base = (size_t)(n * T_SEQ + qrow) * ldo + h * 64;
#pragma unroll
        for (int st = 0; st < 4; ++st)
            O[base + st * 16 + col] = f2bf(o_acc[st][r] * inv);
    }
}

extern "C" void kernel_launch(void* const* d_in, const int* in_sizes, int n_in,
                              void* d_out, int out_size, void* d_ws, size_t ws_size,
                              hipStream_t stream) {
    const float* q_seqs = (const float*)d_in[0];
    const float* r_seqs = (const float*)d_in[1];
    const float* mask   = (const float*)d_in[2];
    const float* Wq     = (const float*)d_in[3];
    const float* Wk     = (const float*)d_in[4];
    const float* Wv     = (const float*)d_in[5];
    const float* Wo     = (const float*)d_in[6];

    const size_t R = 4194304;  // region stride in ushorts (8 MiB)
    ushort_t* ws = (ushort_t*)d_ws;
    ushort_t* bfQ  = ws;            // R0: q_seqs bf16; later reused as wsO
    ushort_t* bfR  = ws + R;        // R1: r_seqs bf16; later reused as wsVT
    ushort_t* WqT  = ws + 2 * R;    // R2: WqT | WkvT(2048 rows) | WoT
    ushort_t* WkvT = WqT + 1048576;
    ushort_t* WoT  = WqT + 3145728;
    ushort_t* wsQ  = ws + 3 * R;    // R3
    ushort_t* wsKV = ws + 4 * R;    // R4+R5: [4096][2048]
    ushort_t* wsVT = bfR;
    ushort_t* wsO  = bfQ;

    dim3 blk(256);

    hipLaunchKernelGGL(cvt_bf16_2, dim3(2048, 2), blk, 0, stream, q_seqs, r_seqs, bfQ, bfR);
    hipLaunchKernelGGL(cvt_w4, dim3(16, 16, 4), blk, 0, stream,
                       Wq, Wk, Wv, Wo, WqT, WkvT, WkvT + 1048576, WoT);

    // fused Q + KV projection (768 blocks = 3/CU)
    hipLaunchKernelGGL(gemm_proj, dim3(24, 32), blk, 0, stream,
                       bfQ, WqT, wsQ, bfR, WkvT, wsKV);

    hipLaunchKernelGGL(transpose_v, dim3(32, 16, 2), blk, 0, stream,
                       wsKV + 1024, 2048, wsVT);

    // q-tile 128: 512-thread blocks, grid (16,16,2)
    hipLaunchKernelGGL(attn_nomax, dim3(16, 16, 2), dim3(512), 0, stream,
                       wsQ, 1024, wsKV, 2048, wsVT, mask, wsO, 1024);

    hipLaunchKernelGGL(gemm128, dim3(8, 32), blk, 0, stream,
                       wsO, WoT, d_out, 4096, 1024, 1024, 1.0f, 1);
}